// Round 9
// baseline (390.754 us; speedup 1.0000x reference)
//
#include <hip/hip_runtime.h>
#include <hip/hip_cooperative_groups.h>
#include <cstdint>
#include <cstddef>

#define D 128
#define SCAN_CHUNK 1024

namespace cg = cooperative_groups;

typedef __attribute__((ext_vector_type(8))) __bf16 bf16v8;
typedef __attribute__((ext_vector_type(4))) float f32v4;

__device__ inline unsigned int pack_bf16x2(float a, float b) {
  unsigned int ua = __float_as_uint(a);
  unsigned int ub = __float_as_uint(b);
  ua = (ua + 0x7fffu + ((ua >> 16) & 1u)) >> 16;
  ub = (ub + 0x7fffu + ((ub >> 16) & 1u)) >> 16;
  return ua | (ub << 16);
}
__device__ inline unsigned short pack_bf16(float a) {
  unsigned int u = __float_as_uint(a);
  return (unsigned short)((u + 0x7fffu + ((u >> 16) & 1u)) >> 16);
}
__device__ inline float bf_lo(unsigned int u) { return __uint_as_float(u << 16); }
__device__ inline float bf_hi(unsigned int u) { return __uint_as_float(u & 0xffff0000u); }

struct Params {
  const float* x;
  const float* ev;
  const float* W1; const float* b1;
  const float* W2; const float* b2;
  const float* W3; const float* b3;
  const int* es; const int* ed;
  unsigned int* BA;
  unsigned int* BB;
  int2* sorted;
  unsigned short* Wb;
  int* count; int* rowptr; int* cursor; int* blockSums;
  float* outf;
  int N; int E;
};

// ===========================================================================
// Shared device phases (used by both the cooperative kernel and fallback)
// ===========================================================================

// Dense: out = in @ W^T, bf16 MFMA 16x16x32, 128x128 tile, K split in two
// 64-halves (LDS = 2 x 128x72 shorts = 36.9 KB).
template <int F32IN>
__device__ void dense_phase(const void* in_v, const unsigned short* Wb,
                            unsigned short* out, int M,
                            unsigned short* Hs, unsigned short* Ws,
                            int blk, int nblk) {
  const int tid = threadIdx.x;
  const int w = tid >> 6;
  const int lane = tid & 63;
  const int lane15 = lane & 15;
  const int quad = lane >> 4;
  const int tiles = (M + 127) >> 7;

  for (int t = blk; t < tiles; t += nblk) {
    const int row0 = t << 7;
    f32v4 acc[2][8];
#pragma unroll
    for (int mt = 0; mt < 2; ++mt)
#pragma unroll
      for (int nt = 0; nt < 8; ++nt) acc[mt][nt] = (f32v4){0.f, 0.f, 0.f, 0.f};

#pragma unroll
    for (int kh = 0; kh < 2; ++kh) {
      const uint4* w16 = (const uint4*)Wb;
#pragma unroll
      for (int it = 0; it < 4; ++it) {
        int c = it * 256 + tid;
        int r = c >> 3;
        int ck = c & 7;
        *(uint4*)&Ws[r * 72 + ck * 8] = w16[(size_t)r * 16 + kh * 8 + ck];
      }
      if (F32IN) {
        const float4* in32 = (const float4*)in_v;
#pragma unroll
        for (int it = 0; it < 8; ++it) {
          int c = it * 256 + tid;
          int r = c >> 4;
          int ck = c & 15;
          float4 g = make_float4(0.f, 0.f, 0.f, 0.f);
          if (row0 + r < M) g = in32[(size_t)(row0 + r) * 32 + kh * 16 + ck];
          uint2 pk = make_uint2(pack_bf16x2(g.x, g.y), pack_bf16x2(g.z, g.w));
          *(uint2*)&Hs[r * 72 + ck * 4] = pk;
        }
      } else {
        const uint4* in16 = (const uint4*)in_v;
#pragma unroll
        for (int it = 0; it < 4; ++it) {
          int c = it * 256 + tid;
          int r = c >> 3;
          int ck = c & 7;
          uint4 g = make_uint4(0, 0, 0, 0);
          if (row0 + r < M) g = in16[(size_t)(row0 + r) * 16 + kh * 8 + ck];
          *(uint4*)&Hs[r * 72 + ck * 8] = g;
        }
      }
      __syncthreads();

#pragma unroll
      for (int kt2 = 0; kt2 < 2; ++kt2) {
        const int ko = kt2 * 32 + quad * 8;
        bf16v8 a0 = *(const bf16v8*)&Hs[(w * 32 + lane15) * 72 + ko];
        bf16v8 a1 = *(const bf16v8*)&Hs[(w * 32 + 16 + lane15) * 72 + ko];
#pragma unroll
        for (int nt = 0; nt < 8; ++nt) {
          bf16v8 b = *(const bf16v8*)&Ws[(nt * 16 + lane15) * 72 + ko];
          acc[0][nt] = __builtin_amdgcn_mfma_f32_16x16x32_bf16(a0, b, acc[0][nt], 0, 0, 0);
          acc[1][nt] = __builtin_amdgcn_mfma_f32_16x16x32_bf16(a1, b, acc[1][nt], 0, 0, 0);
        }
      }
      __syncthreads();
    }

#pragma unroll
    for (int mt = 0; mt < 2; ++mt) {
#pragma unroll
      for (int r = 0; r < 4; ++r) {
        int grow = row0 + w * 32 + mt * 16 + quad * 4 + r;
        if (grow < M) {
#pragma unroll
          for (int nt = 0; nt < 8; ++nt) {
            out[(size_t)grow * D + nt * 16 + lane15] = pack_bf16(acc[mt][nt][r]);
          }
        }
      }
    }
  }
}

// SpMM (round-7 latency form). MODE 0: bias+sigmoid->bf16. MODE 1: softmax->f32.
template <int MODE>
__device__ void spmm_phase(const unsigned int* h, const int2* sorted,
                           const int* rowptr, const int* count,
                           const float* bias, void* out_v, int n, int E,
                           int blk, int nblk) {
  const int wave = threadIdx.x >> 6;
  const int lane = threadIdx.x & 63;
  const int half = lane >> 5;
  const int l = lane & 31;
  const int Em1 = E - 1;
  const uint2* h2 = (const uint2*)h;
  const int quads = (n + 3) >> 2;
  const float4 bb = ((const float4*)bias)[l];

  for (int q = blk; q < quads; q += nblk) {
    int row = q * 4 + wave;
    row = __builtin_amdgcn_readfirstlane(row);
    if (row >= n) continue;
    const int start = rowptr[row];
    const int len = count[row];
    const int lm1 = (len > 0) ? (len - 1) : 0;

    float a0 = 0.f, a1 = 0.f, a2 = 0.f, a3 = 0.f;
#pragma unroll
    for (int k = 0; k < 8; k += 2) {
      int i0 = (k < lm1) ? k : lm1;
      int i1 = (k + 1 < lm1) ? (k + 1) : lm1;
      int e0 = start + i0; if (e0 > Em1) e0 = Em1;
      int e1 = start + i1; if (e1 > Em1) e1 = Em1;
      int2 r0 = sorted[e0];
      int2 r1 = sorted[e1];
      int s = half ? r1.x : r0.x;
      float v = __int_as_float(half ? r1.y : r0.y);
      if (k + half >= len) v = 0.f;
      uint2 u = h2[(size_t)s * 32 + l];
      a0 += v * bf_lo(u.x); a1 += v * bf_hi(u.x);
      a2 += v * bf_lo(u.y); a3 += v * bf_hi(u.y);
    }
    for (int j = 8; j < len; ++j) {
      int2 r = sorted[start + j];
      float v = (half == 0) ? __int_as_float(r.y) : 0.f;
      uint2 u = h2[(size_t)r.x * 32 + l];
      a0 += v * bf_lo(u.x); a1 += v * bf_hi(u.x);
      a2 += v * bf_lo(u.y); a3 += v * bf_hi(u.y);
    }

    a0 += __shfl_xor(a0, 32);
    a1 += __shfl_xor(a1, 32);
    a2 += __shfl_xor(a2, 32);
    a3 += __shfl_xor(a3, 32);

    float t0 = a0 + bb.x, t1 = a1 + bb.y, t2 = a2 + bb.z, t3 = a3 + bb.w;

    if (MODE == 0) {
      if (half == 0) {
        uint2 pk;
        pk.x = pack_bf16x2(1.0f / (1.0f + __expf(-t0)), 1.0f / (1.0f + __expf(-t1)));
        pk.y = pack_bf16x2(1.0f / (1.0f + __expf(-t2)), 1.0f / (1.0f + __expf(-t3)));
        ((uint2*)out_v)[(size_t)row * 32 + l] = pk;
      }
    } else {
      float m = fmaxf(fmaxf(t0, t1), fmaxf(t2, t3));
#pragma unroll
      for (int off = 16; off; off >>= 1) m = fmaxf(m, __shfl_xor(m, off));
      float e0 = __expf(t0 - m), e1 = __expf(t1 - m);
      float e2 = __expf(t2 - m), e3 = __expf(t3 - m);
      float s = (e0 + e1) + (e2 + e3);
#pragma unroll
      for (int off = 16; off; off >>= 1) s += __shfl_xor(s, off);
      float inv = 1.0f / s;
      if (half == 0) {
        ((float4*)out_v)[(size_t)row * 32 + l] =
            make_float4(e0 * inv, e1 * inv, e2 * inv, e3 * inv);
      }
    }
  }
}

// ===========================================================================
// Cooperative all-in-one kernel
// ===========================================================================
__global__ void __launch_bounds__(256, 4) gcn_all(Params p) {
  cg::grid_group g = cg::this_grid();
  __shared__ __align__(16) unsigned short SMEM[2 * 128 * 72];  // 36.9 KB
  unsigned short* Hs = SMEM;
  unsigned short* Ws = SMEM + 128 * 72;
  int* sdata = (int*)SMEM;

  const int tid = threadIdx.x;
  const int gtid = blockIdx.x * 256 + tid;
  const int gstride = gridDim.x * 256;
  const int N = p.N, E = p.E;
  const int nblkScan = (N + 1023) >> 10;

  for (int i = gtid; i < N; i += gstride) p.count[i] = 0;
  {
    const float* srcw[3] = {p.W1, p.W2, p.W3};
    for (int i = gtid; i < 3 * D * D; i += gstride)
      p.Wb[i] = pack_bf16(srcw[i >> 14][i & (D * D - 1)]);
  }
  g.sync();

  for (int e = gtid; e < E; e += gstride) atomicAdd(&p.count[p.ed[e]], 1);
  g.sync();

  for (int cb = blockIdx.x; cb < nblkScan; cb += gridDim.x) {
    const int base = cb << 10;
    int v[4];
#pragma unroll
    for (int k = 0; k < 4; ++k) {
      int idx = base + tid * 4 + k;
      v[k] = (idx < N) ? p.count[idx] : 0;
    }
    int s = v[0] + v[1] + v[2] + v[3];
    sdata[tid] = s;
    __syncthreads();
    for (int off = 1; off < 256; off <<= 1) {
      int xv = (tid >= off) ? sdata[tid - off] : 0;
      __syncthreads();
      sdata[tid] += xv;
      __syncthreads();
    }
    int run = sdata[tid] - s;
#pragma unroll
    for (int k = 0; k < 4; ++k) {
      int idx = base + tid * 4 + k;
      if (idx < N) p.rowptr[idx] = run;
      run += v[k];
    }
    if (tid == 255) p.blockSums[cb] = sdata[255];
    __syncthreads();
  }
  g.sync();

  if (blockIdx.x == 0) {
    int v[4];
#pragma unroll
    for (int k = 0; k < 4; ++k) {
      int idx = tid * 4 + k;
      v[k] = (idx < nblkScan) ? p.blockSums[idx] : 0;
    }
    int s = v[0] + v[1] + v[2] + v[3];
    sdata[tid] = s;
    __syncthreads();
    for (int off = 1; off < 256; off <<= 1) {
      int xv = (tid >= off) ? sdata[tid - off] : 0;
      __syncthreads();
      sdata[tid] += xv;
      __syncthreads();
    }
    int run = sdata[tid] - s;
#pragma unroll
    for (int k = 0; k < 4; ++k) {
      int idx = tid * 4 + k;
      if (idx < nblkScan) { int t = v[k]; p.blockSums[idx] = run; run += t; }
    }
  }
  g.sync();

  for (int i = gtid; i < N; i += gstride) {
    int v = p.rowptr[i] + p.blockSums[i >> 10];
    p.rowptr[i] = v;
    p.cursor[i] = v;
  }
  g.sync();

  for (int e = gtid; e < E; e += gstride) {
    int t = p.ed[e];
    int pos = atomicAdd(&p.cursor[t], 1);
    p.sorted[pos] = make_int2(p.es[e], __float_as_int(p.ev[e]));
  }
  g.sync();

  dense_phase<1>(p.x, p.Wb + 0 * D * D, (unsigned short*)p.BA, N, Hs, Ws,
                 blockIdx.x, gridDim.x);
  g.sync();
  spmm_phase<0>(p.BA, p.sorted, p.rowptr, p.count, p.b1, p.BB, N, E,
                blockIdx.x, gridDim.x);
  g.sync();
  dense_phase<0>(p.BB, p.Wb + 1 * D * D, (unsigned short*)p.BA, N, Hs, Ws,
                 blockIdx.x, gridDim.x);
  g.sync();
  spmm_phase<0>(p.BA, p.sorted, p.rowptr, p.count, p.b2, p.BB, N, E,
                blockIdx.x, gridDim.x);
  g.sync();
  dense_phase<0>(p.BB, p.Wb + 2 * D * D, (unsigned short*)p.BA, N, Hs, Ws,
                 blockIdx.x, gridDim.x);
  g.sync();
  spmm_phase<1>(p.BA, p.sorted, p.rowptr, p.count, p.b3, p.outf, N, E,
                blockIdx.x, gridDim.x);
}

// ===========================================================================
// Fallback multi-kernel pipeline (round-7, known-good 343us)
// ===========================================================================
__global__ __launch_bounds__(256) void hist_kernel(
    const int* __restrict__ dst, int* __restrict__ count, int E) {
  int e = blockIdx.x * 256 + threadIdx.x;
  if (e < E) atomicAdd(&count[dst[e]], 1);
}

__global__ __launch_bounds__(256) void zero_kernel(int* __restrict__ a, int n) {
  int i = blockIdx.x * 256 + threadIdx.x;
  if (i < n) a[i] = 0;
}

__global__ __launch_bounds__(256) void scan_blocks(
    const int* __restrict__ count, int* __restrict__ rowptr,
    int* __restrict__ blockSums, int n) {
  __shared__ int sdata[256];
  const int tid = threadIdx.x;
  const int base = blockIdx.x * SCAN_CHUNK;
  int v[4];
#pragma unroll
  for (int k = 0; k < 4; ++k) {
    int idx = base + tid * 4 + k;
    v[k] = (idx < n) ? count[idx] : 0;
  }
  int s = v[0] + v[1] + v[2] + v[3];
  sdata[tid] = s;
  __syncthreads();
  for (int off = 1; off < 256; off <<= 1) {
    int x = (tid >= off) ? sdata[tid - off] : 0;
    __syncthreads();
    sdata[tid] += x;
    __syncthreads();
  }
  int run = sdata[tid] - s;
#pragma unroll
  for (int k = 0; k < 4; ++k) {
    int idx = base + tid * 4 + k;
    if (idx < n) rowptr[idx] = run;
    run += v[k];
  }
  if (tid == 255) blockSums[blockIdx.x] = sdata[255];
}

__global__ __launch_bounds__(256) void scan_top(int* __restrict__ bs, int nblk) {
  __shared__ int sdata[256];
  const int tid = threadIdx.x;
  int v[4];
#pragma unroll
  for (int k = 0; k < 4; ++k) {
    int idx = tid * 4 + k;
    v[k] = (idx < nblk) ? bs[idx] : 0;
  }
  int s = v[0] + v[1] + v[2] + v[3];
  sdata[tid] = s;
  __syncthreads();
  for (int off = 1; off < 256; off <<= 1) {
    int x = (tid >= off) ? sdata[tid - off] : 0;
    __syncthreads();
    sdata[tid] += x;
    __syncthreads();
  }
  int run = sdata[tid] - s;
#pragma unroll
  for (int k = 0; k < 4; ++k) {
    int idx = tid * 4 + k;
    if (idx < nblk) { int t = v[k]; bs[idx] = run; run += t; }
  }
}

__global__ __launch_bounds__(256) void add_offsets(
    int* __restrict__ rowptr, int* __restrict__ cursor,
    const int* __restrict__ bs, int n) {
  int i = blockIdx.x * 256 + threadIdx.x;
  if (i < n) {
    int v = rowptr[i] + bs[i >> 10];
    rowptr[i] = v;
    cursor[i] = v;
  }
}

__global__ __launch_bounds__(256) void scatter_edges(
    const int* __restrict__ src, const int* __restrict__ dst,
    const float* __restrict__ val, int* __restrict__ cursor,
    int2* __restrict__ sorted, int E) {
  int e = blockIdx.x * 256 + threadIdx.x;
  if (e < E) {
    int t = dst[e];
    int pos = atomicAdd(&cursor[t], 1);
    sorted[pos] = make_int2(src[e], __float_as_int(val[e]));
  }
}

__global__ __launch_bounds__(256) void cast_w(
    const float* __restrict__ W1, const float* __restrict__ W2,
    const float* __restrict__ W3, unsigned short* __restrict__ out) {
  const float* src[3] = {W1, W2, W3};
  int m = blockIdx.y;
  int i = blockIdx.x * 256 + threadIdx.x;
  if (i < D * D) out[(size_t)m * D * D + i] = pack_bf16(src[m][i]);
}

template <int F32IN>
__global__ __launch_bounds__(256) void dense_nt(
    const void* __restrict__ in_v, const unsigned short* __restrict__ Wb,
    unsigned short* __restrict__ out, int M) {
  __shared__ __align__(16) unsigned short SM[2 * 128 * 72];
  dense_phase<F32IN>(in_v, Wb, out, M, SM, SM + 128 * 72, blockIdx.x, gridDim.x);
}

template <int MODE>
__global__ __launch_bounds__(256) void spmm_fused(
    const unsigned int* __restrict__ h, const int2* __restrict__ sorted,
    const int* __restrict__ rowptr, const int* __restrict__ count,
    const float* __restrict__ bias, void* __restrict__ out_v, int n, int E) {
  spmm_phase<MODE>(h, sorted, rowptr, count, bias, out_v, n, E,
                   blockIdx.x, gridDim.x);
}

// ===========================================================================
extern "C" void kernel_launch(void* const* d_in, const int* in_sizes, int n_in,
                              void* d_out, int out_size, void* d_ws, size_t ws_size,
                              hipStream_t stream) {
  const int N = in_sizes[0] / D;
  const int E = in_sizes[1];

  char* pp = (char*)d_ws;
  unsigned int* BA = (unsigned int*)pp; pp += (size_t)N * 64 * sizeof(unsigned int);
  unsigned int* BB = (unsigned int*)pp; pp += (size_t)N * 64 * sizeof(unsigned int);
  int2* sorted = (int2*)pp;            pp += (size_t)E * sizeof(int2);
  unsigned short* Wb = (unsigned short*)pp; pp += 3 * (size_t)D * D * sizeof(unsigned short);
  int* count  = (int*)pp;              pp += (size_t)N * sizeof(int);
  int* rowptr = (int*)pp;              pp += (size_t)N * sizeof(int);
  int* cursor = (int*)pp;              pp += (size_t)N * sizeof(int);
  int* blockSums = (int*)pp;           pp += 1024 * sizeof(int);

  Params prm;
  prm.x  = (const float*)d_in[0];
  prm.ev = (const float*)d_in[1];
  prm.W1 = (const float*)d_in[2]; prm.b1 = (const float*)d_in[3];
  prm.W2 = (const float*)d_in[4]; prm.b2 = (const float*)d_in[5];
  prm.W3 = (const float*)d_in[6]; prm.b3 = (const float*)d_in[7];
  prm.es = (const int*)d_in[8];   prm.ed = (const int*)d_in[9];
  prm.BA = BA; prm.BB = BB; prm.sorted = sorted; prm.Wb = Wb;
  prm.count = count; prm.rowptr = rowptr; prm.cursor = cursor;
  prm.blockSums = blockSums;
  prm.outf = (float*)d_out;
  prm.N = N; prm.E = E;

  // Size the cooperative grid from the runtime's occupancy answer (the
  // round-8 hard-coded 1024 was rejected: nothing launched, output stayed 0).
  int occ = 0;
  hipError_t qerr = hipOccupancyMaxActiveBlocksPerMultiprocessor(
      &occ, (const void*)gcn_all, 256, 0);
  int numCU = 0;
  hipError_t aerr = hipDeviceGetAttribute(
      &numCU, hipDeviceAttributeMultiprocessorCount, 0);

  int coop_grid = 0;
  if (qerr == hipSuccess && aerr == hipSuccess && occ > 0 && numCU > 0) {
    coop_grid = occ * numCU;
    if (coop_grid > 1024) coop_grid = 1024;
  }

  if (coop_grid >= 256) {
    void* args[] = {&prm};
    (void)hipLaunchCooperativeKernel((void*)gcn_all, dim3(coop_grid), dim3(256),
                                     args, 0, stream);
    return;
  }

  // ---- Fallback: round-7 multi-kernel pipeline ----
  const int eblk = (E + 255) / 256;
  const int nblk256 = (N + 255) / 256;
  const int nblkScan = (N + SCAN_CHUNK - 1) / SCAN_CHUNK;
  const int rowgrid = (N + 3) / 4;
  const int dense_grid = (N + 127) / 128;

  zero_kernel<<<nblk256, 256, 0, stream>>>(count, N);
  hist_kernel<<<eblk, 256, 0, stream>>>(prm.ed, count, E);
  cast_w<<<dim3((D * D + 255) / 256, 3), 256, 0, stream>>>(prm.W1, prm.W2, prm.W3, Wb);
  scan_blocks<<<nblkScan, 256, 0, stream>>>(count, rowptr, blockSums, N);
  scan_top<<<1, 256, 0, stream>>>(blockSums, nblkScan);
  add_offsets<<<nblk256, 256, 0, stream>>>(rowptr, cursor, blockSums, N);
  scatter_edges<<<eblk, 256, 0, stream>>>(prm.es, prm.ed, prm.ev, cursor, sorted, E);

  dense_nt<1><<<dense_grid, 256, 0, stream>>>(prm.x, Wb + 0 * D * D,
                                              (unsigned short*)BA, N);
  spmm_fused<0><<<rowgrid, 256, 0, stream>>>(BA, sorted, rowptr, count, prm.b1, BB, N, E);
  dense_nt<0><<<dense_grid, 256, 0, stream>>>(BB, Wb + 1 * D * D,
                                              (unsigned short*)BA, N);
  spmm_fused<0><<<rowgrid, 256, 0, stream>>>(BA, sorted, rowptr, count, prm.b2, BB, N, E);
  dense_nt<0><<<dense_grid, 256, 0, stream>>>(BB, Wb + 2 * D * D,
                                              (unsigned short*)BA, N);
  spmm_fused<1><<<rowgrid, 256, 0, stream>>>(BA, sorted, rowptr, count, prm.b3, d_out, N, E);
}